// Round 1
// baseline (1246.025 us; speedup 1.0000x reference)
//
#include <hip/hip_runtime.h>

typedef __attribute__((ext_vector_type(8))) short short8;
typedef __attribute__((ext_vector_type(4))) float f32x4;
typedef __attribute__((ext_vector_type(4))) unsigned short us4;

#define L_ 2048
#define E_ 512
#define SCALE 0.04419417382415922f  // 1/sqrt(512)

__device__ __forceinline__ unsigned short f2bf(float f) {
  unsigned u = __builtin_bit_cast(unsigned, f);
  u += 0x7FFFu + ((u >> 16) & 1u);   // RNE
  return (unsigned short)(u >> 16);
}
__device__ __forceinline__ float bf2f(unsigned short h) {
  return __builtin_bit_cast(float, (unsigned)h << 16);
}

// 8 waves: we = e-chunk (0..3) of 128 for QK^T K-reduction split,
//          ws = s-half (0..1) of the 32-wide KV chunk.
// PV: wave w owns d-chunk [w*64, w*64+64).
__launch_bounds__(512, 2)
__global__ void fattn_kernel(const float* __restrict__ Q,
                             const float* __restrict__ K,
                             const float* __restrict__ V,
                             float* __restrict__ O) {
  __shared__ __align__(16) unsigned short Vt[4][512][8];      // V^T chunk: [s>>3][d][s&7]
  __shared__ __align__(16) unsigned short Sp[4][2][4][64][4]; // partial scores [we][ws][mt][lane][reg]
  __shared__ __align__(16) unsigned short P2[4][64][8];       // P: [s>>3][q][s&7]

  const int tid  = threadIdx.x;
  const int w    = tid >> 6;
  const int lane = tid & 63;
  const int g    = lane >> 4;
  const int ln   = lane & 15;
  const int we   = w >> 1;
  const int ws   = w & 1;
  const int bz   = blockIdx.y;
  const int q0   = (31 - blockIdx.x) * 64;   // heavy tiles dispatch first

  const float* Qb = Q + (size_t)bz * (L_ * E_);
  const float* Kb = K + (size_t)bz * (L_ * E_);
  const float* Vb = V + (size_t)bz * (L_ * E_);

  // Q fragments for this wave's e-chunk, held in registers for all iterations.
  // A-frag (16x16x32): row q = lane&15 (+16*mt), k = (lane>>4)*8 + i within 32-chunk.
  short8 qf[4][4];
#pragma unroll
  for (int mt = 0; mt < 4; ++mt) {
    const float* qp = Qb + (size_t)(q0 + mt * 16 + ln) * E_ + (we * 128 + g * 8);
#pragma unroll
    for (int k = 0; k < 4; ++k) {
      f32x4 a = *(const f32x4*)(qp + k * 32);
      f32x4 b = *(const f32x4*)(qp + k * 32 + 4);
      short8 t;
      t[0] = (short)f2bf(a[0]); t[1] = (short)f2bf(a[1]);
      t[2] = (short)f2bf(a[2]); t[3] = (short)f2bf(a[3]);
      t[4] = (short)f2bf(b[0]); t[5] = (short)f2bf(b[1]);
      t[6] = (short)f2bf(b[2]); t[7] = (short)f2bf(b[3]);
      qf[mt][k] = t;
    }
  }

  f32x4 acc[4][4];
#pragma unroll
  for (int mt = 0; mt < 4; ++mt)
#pragma unroll
    for (int n = 0; n < 4; ++n) acc[mt][n] = (f32x4){0.f, 0.f, 0.f, 0.f};

  float m_run[4][4], l_run[4][4];
#pragma unroll
  for (int mt = 0; mt < 4; ++mt)
#pragma unroll
    for (int r = 0; r < 4; ++r) { m_run[mt][r] = -1e30f; l_run[mt][r] = 0.f; }

  const int nIter = q0 / 32 + 2;   // cover s <= q0+63
  for (int it = 0; it < nIter; ++it) {
    const int s0 = it * 32;

    // ---------- Phase A: stage V^T to LDS; QK^T partials via MFMA ----------
    {
      // thread tid owns column d = tid; coalesced scalar loads along d
      const float* vp = Vb + (size_t)s0 * E_ + tid;
#pragma unroll
      for (int s4 = 0; s4 < 32; s4 += 4) {
        float v0 = vp[(size_t)(s4 + 0) * E_];
        float v1 = vp[(size_t)(s4 + 1) * E_];
        float v2 = vp[(size_t)(s4 + 2) * E_];
        float v3 = vp[(size_t)(s4 + 3) * E_];
        us4 u; u[0] = f2bf(v0); u[1] = f2bf(v1); u[2] = f2bf(v2); u[3] = f2bf(v3);
        *(us4*)&Vt[s4 >> 3][tid][s4 & 7] = u;
      }
    }

    f32x4 ps[4];
#pragma unroll
    for (int mt = 0; mt < 4; ++mt) ps[mt] = (f32x4){0.f, 0.f, 0.f, 0.f};
    {
      // B-frag: col s = lane&15 (+16*ws), k = e-offset (lane>>4)*8+i ; K row-major fits
      const float* kp = Kb + (size_t)(s0 + ws * 16 + ln) * E_ + (we * 128 + g * 8);
#pragma unroll
      for (int k = 0; k < 4; ++k) {
        f32x4 a = *(const f32x4*)(kp + k * 32);
        f32x4 b = *(const f32x4*)(kp + k * 32 + 4);
        short8 kf;
        kf[0] = (short)f2bf(a[0]); kf[1] = (short)f2bf(a[1]);
        kf[2] = (short)f2bf(a[2]); kf[3] = (short)f2bf(a[3]);
        kf[4] = (short)f2bf(b[0]); kf[5] = (short)f2bf(b[1]);
        kf[6] = (short)f2bf(b[2]); kf[7] = (short)f2bf(b[3]);
#pragma unroll
        for (int mt = 0; mt < 4; ++mt)
          ps[mt] = __builtin_amdgcn_mfma_f32_16x16x32_bf16(qf[mt][k], kf, ps[mt], 0, 0, 0);
      }
    }
#pragma unroll
    for (int mt = 0; mt < 4; ++mt) {
      us4 u;
      u[0] = f2bf(ps[mt][0]); u[1] = f2bf(ps[mt][1]);
      u[2] = f2bf(ps[mt][2]); u[3] = f2bf(ps[mt][3]);
      *(us4*)&Sp[we][ws][mt][lane][0] = u;
    }
    __syncthreads();

    // ---------- Phase B: reduce partials, online softmax, write P ----------
    const bool diag = (s0 + 31 > q0);
#pragma unroll
    for (int mt = 0; mt < 4; ++mt) {
      float sc[2][4];
#pragma unroll
      for (int nt = 0; nt < 2; ++nt) {
        float s0r = 0.f, s1r = 0.f, s2r = 0.f, s3r = 0.f;
#pragma unroll
        for (int e = 0; e < 4; ++e) {
          us4 u = *(us4*)&Sp[e][nt][mt][lane][0];
          s0r += bf2f(u[0]); s1r += bf2f(u[1]); s2r += bf2f(u[2]); s3r += bf2f(u[3]);
        }
        sc[nt][0] = s0r * SCALE; sc[nt][1] = s1r * SCALE;
        sc[nt][2] = s2r * SCALE; sc[nt][3] = s3r * SCALE;
      }
      if (diag) {
#pragma unroll
        for (int nt = 0; nt < 2; ++nt)
#pragma unroll
          for (int r = 0; r < 4; ++r)
            if (s0 + nt * 16 + ln > q0 + mt * 16 + g * 4 + r) sc[nt][r] = -1e30f;
      }
      float tmax[4], tsum[4], corr[4], p[2][4];
#pragma unroll
      for (int r = 0; r < 4; ++r) tmax[r] = fmaxf(sc[0][r], sc[1][r]);
#pragma unroll
      for (int off = 1; off < 16; off <<= 1)
#pragma unroll
        for (int r = 0; r < 4; ++r) tmax[r] = fmaxf(tmax[r], __shfl_xor(tmax[r], off));
#pragma unroll
      for (int r = 0; r < 4; ++r) {
        float mn = fmaxf(m_run[mt][r], tmax[r]);
        corr[r] = __expf(m_run[mt][r] - mn);
        m_run[mt][r] = mn;
        tsum[r] = 0.f;
      }
#pragma unroll
      for (int nt = 0; nt < 2; ++nt)
#pragma unroll
        for (int r = 0; r < 4; ++r) {
          p[nt][r] = __expf(sc[nt][r] - m_run[mt][r]);
          tsum[r] += p[nt][r];
        }
#pragma unroll
      for (int off = 1; off < 16; off <<= 1)
#pragma unroll
        for (int r = 0; r < 4; ++r) tsum[r] += __shfl_xor(tsum[r], off);
#pragma unroll
      for (int r = 0; r < 4; ++r) l_run[mt][r] = l_run[mt][r] * corr[r] + tsum[r];
#pragma unroll
      for (int n = 0; n < 4; ++n)
#pragma unroll
        for (int r = 0; r < 4; ++r) acc[mt][n][r] *= corr[r];
      if (w == mt) {  // waves 0..3 each publish one 16-row stripe of P
#pragma unroll
        for (int nt = 0; nt < 2; ++nt)
#pragma unroll
          for (int r = 0; r < 4; ++r) {
            int q = mt * 16 + g * 4 + r;
            int s = nt * 16 + ln;
            P2[s >> 3][q][s & 7] = f2bf(p[nt][r]);
          }
      }
    }
    __syncthreads();

    // ---------- Phase C: PV MFMA (wave w owns d in [w*64, w*64+64)) ----------
    short8 pa[4];
#pragma unroll
    for (int mt = 0; mt < 4; ++mt)
      pa[mt] = *(const short8*)&P2[g][mt * 16 + ln][0];
#pragma unroll
    for (int n = 0; n < 4; ++n) {
      short8 vb = *(const short8*)&Vt[g][w * 64 + n * 16 + ln][0];
#pragma unroll
      for (int mt = 0; mt < 4; ++mt)
        acc[mt][n] = __builtin_amdgcn_mfma_f32_16x16x32_bf16(pa[mt], vb, acc[mt][n], 0, 0, 0);
    }
    __syncthreads();
  }

  // ---------- epilogue: divide by softmax denom, store fp32 ----------
  float* Ob = O + (size_t)bz * (L_ * E_);
#pragma unroll
  for (int mt = 0; mt < 4; ++mt) {
    float inv[4];
#pragma unroll
    for (int r = 0; r < 4; ++r) inv[r] = 1.0f / l_run[mt][r];
#pragma unroll
    for (int n = 0; n < 4; ++n) {
      const int col = w * 64 + n * 16 + ln;
#pragma unroll
      for (int r = 0; r < 4; ++r)
        Ob[(size_t)(q0 + mt * 16 + g * 4 + r) * E_ + col] = acc[mt][n][r] * inv[r];
    }
  }
}

extern "C" void kernel_launch(void* const* d_in, const int* in_sizes, int n_in,
                              void* d_out, int out_size, void* d_ws, size_t ws_size,
                              hipStream_t stream) {
  const float* Q = (const float*)d_in[0];
  const float* K = (const float*)d_in[1];
  const float* V = (const float*)d_in[2];
  float* O = (float*)d_out;
  dim3 grid(32, 16);  // x = q-tile (64 rows), y = batch
  fattn_kernel<<<grid, 512, 0, stream>>>(Q, K, V, O);
}

// Round 2
// 446.337 us; speedup vs baseline: 2.7917x; 2.7917x over previous
//
#include <hip/hip_runtime.h>
#include <hip/hip_bf16.h>

typedef __attribute__((ext_vector_type(8))) short short8;
typedef __attribute__((ext_vector_type(4))) float f32x4;
typedef __attribute__((ext_vector_type(4))) unsigned short us4;

#define L_ 2048
#define E_ 512
#define SCALE 0.04419417382415922f  // 1/sqrt(512)

static __device__ __forceinline__ unsigned short f2bf(float f) {
  return __builtin_bit_cast(unsigned short, __float2bfloat16(f));
}
static __device__ __forceinline__ float bf2f(unsigned short u) {
  return __builtin_bit_cast(float, (unsigned)u << 16);
}

// 8 waves: QK^T split as we(0..3: 128-e chunk) x ws(0..1: 32-s half of 64-s tile).
// Softmax: waves 0..3 each own one 16-q stripe (mt = w); stats canonical in LDS.
// PV: wave w owns d-chunk [w*64, w*64+64); V lives in registers (no LDS staging).
__launch_bounds__(512, 1)
__global__ void fattn_kernel(const float* __restrict__ Q,
                             const float* __restrict__ K,
                             const float* __restrict__ V,
                             float* __restrict__ O) {
  __shared__ us4 Sp[4][2][4][2][64];        // bf16x4 partial scores [we][ws][mt][nt][lane], 32 KB
  __shared__ unsigned short P2[8][64][8];   // P in A-frag layout [s>>3][q][s&7], 8 KB
  __shared__ float m_s[64], l_s[64], corr_s[64];

  const int tid  = threadIdx.x;
  const int w    = tid >> 6;
  const int lane = tid & 63;
  const int g    = lane >> 4;
  const int ln   = lane & 15;
  const int we   = w >> 1;
  const int ws   = w & 1;
  const int bz   = blockIdx.y;
  const int q0   = (31 - (int)blockIdx.x) * 64;   // heavy tiles dispatch first

  const float* Qb = Q + (size_t)bz * (L_ * E_);
  const float* Kb = K + (size_t)bz * (L_ * E_);
  const float* Vb = V + (size_t)bz * (L_ * E_);

  if (tid < 64) { m_s[tid] = -1e30f; l_s[tid] = 0.f; }

  // Q fragments (SCALE pre-folded), e-chunk we*128, kept in regs all iterations.
  short8 qf[4][4];
#pragma unroll
  for (int mt = 0; mt < 4; ++mt) {
    const float* qp = Qb + (size_t)(q0 + mt * 16 + ln) * E_ + (we * 128 + g * 8);
#pragma unroll
    for (int kc = 0; kc < 4; ++kc) {
      f32x4 a = *(const f32x4*)(qp + kc * 32);
      f32x4 b = *(const f32x4*)(qp + kc * 32 + 4);
      short8 t;
      t[0] = (short)f2bf(a[0] * SCALE); t[1] = (short)f2bf(a[1] * SCALE);
      t[2] = (short)f2bf(a[2] * SCALE); t[3] = (short)f2bf(a[3] * SCALE);
      t[4] = (short)f2bf(b[0] * SCALE); t[5] = (short)f2bf(b[1] * SCALE);
      t[6] = (short)f2bf(b[2] * SCALE); t[7] = (short)f2bf(b[3] * SCALE);
      qf[mt][kc] = t;
    }
  }

  f32x4 acc[4][4];
#pragma unroll
  for (int mt = 0; mt < 4; ++mt)
#pragma unroll
    for (int n = 0; n < 4; ++n) acc[mt][n] = (f32x4){0.f, 0.f, 0.f, 0.f};

  const int nIter = q0 / 64 + 1;   // covers s <= q0+63
  for (int it = 0; it < nIter; ++it) {
    const int s0 = it * 64;

    // ---- Phase A ----
    // Issue first-half V loads (s0..s0+31) for this iter; consumed in Phase C.
    // No barrier precedes this, so these overlap the previous iteration's PV.
    float vr0[4][8];
#pragma unroll
    for (int n = 0; n < 4; ++n) {
      const float* vp = Vb + (size_t)(s0 + g * 8) * E_ + (w * 64 + n * 16 + ln);
#pragma unroll
      for (int i = 0; i < 8; ++i) vr0[n][i] = vp[(size_t)i * E_];
    }

    // QK^T partials: this wave covers 64q x 16s (nt) x 128e (we)
#pragma unroll
    for (int nt = 0; nt < 2; ++nt) {
      f32x4 ps[4];
#pragma unroll
      for (int mt = 0; mt < 4; ++mt) ps[mt] = (f32x4){0.f, 0.f, 0.f, 0.f};
      const float* kp = Kb + (size_t)(s0 + ws * 32 + nt * 16 + ln) * E_ + (we * 128 + g * 8);
#pragma unroll
      for (int kc = 0; kc < 4; ++kc) {
        f32x4 a = *(const f32x4*)(kp + kc * 32);
        f32x4 b = *(const f32x4*)(kp + kc * 32 + 4);
        short8 kf;
        kf[0] = (short)f2bf(a[0]); kf[1] = (short)f2bf(a[1]);
        kf[2] = (short)f2bf(a[2]); kf[3] = (short)f2bf(a[3]);
        kf[4] = (short)f2bf(b[0]); kf[5] = (short)f2bf(b[1]);
        kf[6] = (short)f2bf(b[2]); kf[7] = (short)f2bf(b[3]);
#pragma unroll
        for (int mt = 0; mt < 4; ++mt)
          ps[mt] = __builtin_amdgcn_mfma_f32_16x16x32_bf16(qf[mt][kc], kf, ps[mt], 0, 0, 0);
      }
#pragma unroll
      for (int mt = 0; mt < 4; ++mt) {
        us4 u;
        u[0] = f2bf(ps[mt][0]); u[1] = f2bf(ps[mt][1]);
        u[2] = f2bf(ps[mt][2]); u[3] = f2bf(ps[mt][3]);
        Sp[we][ws][mt][nt][lane] = u;
      }
    }
    __syncthreads();   // barrier 1: Sp ready

    // ---- Phase B: waves 0..3 reduce + online softmax for stripe mt = w ----
    if (w < 4) {
      const int mt = w;
      float p[4][4];
#pragma unroll
      for (int j = 0; j < 4; ++j) {   // j = ws*2 + nt -> s = j*16 + ln
        us4 u0 = Sp[0][j >> 1][mt][j & 1][lane];
        us4 u1 = Sp[1][j >> 1][mt][j & 1][lane];
        us4 u2 = Sp[2][j >> 1][mt][j & 1][lane];
        us4 u3 = Sp[3][j >> 1][mt][j & 1][lane];
#pragma unroll
        for (int r = 0; r < 4; ++r)
          p[j][r] = bf2f(u0[r]) + bf2f(u1[r]) + bf2f(u2[r]) + bf2f(u3[r]);
      }
      if (s0 + 63 > q0) {
#pragma unroll
        for (int j = 0; j < 4; ++j)
#pragma unroll
          for (int r = 0; r < 4; ++r)
            if (s0 + j * 16 + ln > q0 + mt * 16 + g * 4 + r) p[j][r] = -1e30f;
      }
      float tmax[4], lsum[4];
#pragma unroll
      for (int r = 0; r < 4; ++r)
        tmax[r] = fmaxf(fmaxf(p[0][r], p[1][r]), fmaxf(p[2][r], p[3][r]));
#pragma unroll
      for (int off = 1; off < 16; off <<= 1)
#pragma unroll
        for (int r = 0; r < 4; ++r) tmax[r] = fmaxf(tmax[r], __shfl_xor(tmax[r], off));
      f32x4 mr = *(const f32x4*)&m_s[mt * 16 + g * 4];
      float mnew[4], corr[4];
#pragma unroll
      for (int r = 0; r < 4; ++r) {
        mnew[r] = fmaxf(mr[r], tmax[r]);
        corr[r] = __expf(mr[r] - mnew[r]);
        lsum[r] = 0.f;
      }
#pragma unroll
      for (int j = 0; j < 4; ++j)
#pragma unroll
        for (int r = 0; r < 4; ++r) {
          p[j][r] = __expf(p[j][r] - mnew[r]);
          lsum[r] += p[j][r];
        }
#pragma unroll
      for (int off = 1; off < 16; off <<= 1)
#pragma unroll
        for (int r = 0; r < 4; ++r) lsum[r] += __shfl_xor(lsum[r], off);
      if (ln == 0) {
#pragma unroll
        for (int r = 0; r < 4; ++r) {
          const int q = mt * 16 + g * 4 + r;
          m_s[q] = mnew[r];
          corr_s[q] = corr[r];
          l_s[q] = l_s[q] * corr[r] + lsum[r];
        }
      }
#pragma unroll
      for (int j = 0; j < 4; ++j)
#pragma unroll
        for (int r = 0; r < 4; ++r) {
          const int s = j * 16 + ln;
          P2[s >> 3][mt * 16 + g * 4 + r][s & 7] = f2bf(p[j][r]);
        }
    }
    __syncthreads();   // barrier 2: P2 + stats ready

    // ---- Phase C: rescale + PV ----
    // Issue second-half V loads (s0+32..s0+63) now; latency hides under kc=0 MFMAs.
    float vr1[4][8];
#pragma unroll
    for (int n = 0; n < 4; ++n) {
      const float* vp = Vb + (size_t)(s0 + 32 + g * 8) * E_ + (w * 64 + n * 16 + ln);
#pragma unroll
      for (int i = 0; i < 8; ++i) vr1[n][i] = vp[(size_t)i * E_];
    }
    // convert first-half V
    short8 vf0[4];
#pragma unroll
    for (int n = 0; n < 4; ++n) {
      short8 t;
#pragma unroll
      for (int i = 0; i < 8; ++i) t[i] = (short)f2bf(vr0[n][i]);
      vf0[n] = t;
    }
#pragma unroll
    for (int mt = 0; mt < 4; ++mt) {
      f32x4 c4 = *(const f32x4*)&corr_s[mt * 16 + g * 4];
#pragma unroll
      for (int n = 0; n < 4; ++n) {
        acc[mt][n][0] *= c4[0]; acc[mt][n][1] *= c4[1];
        acc[mt][n][2] *= c4[2]; acc[mt][n][3] *= c4[3];
      }
    }
    {
      short8 pa[4];
#pragma unroll
      for (int mt = 0; mt < 4; ++mt)
        pa[mt] = *(const short8*)&P2[g][mt * 16 + ln][0];
#pragma unroll
      for (int n = 0; n < 4; ++n)
#pragma unroll
        for (int mt = 0; mt < 4; ++mt)
          acc[mt][n] = __builtin_amdgcn_mfma_f32_16x16x32_bf16(pa[mt], vf0[n], acc[mt][n], 0, 0, 0);
    }
    {
      short8 vf1[4];
#pragma unroll
      for (int n = 0; n < 4; ++n) {
        short8 t;
#pragma unroll
        for (int i = 0; i < 8; ++i) t[i] = (short)f2bf(vr1[n][i]);
        vf1[n] = t;
      }
      short8 pa[4];
#pragma unroll
      for (int mt = 0; mt < 4; ++mt)
        pa[mt] = *(const short8*)&P2[4 + g][mt * 16 + ln][0];
#pragma unroll
      for (int n = 0; n < 4; ++n)
#pragma unroll
        for (int mt = 0; mt < 4; ++mt)
          acc[mt][n] = __builtin_amdgcn_mfma_f32_16x16x32_bf16(pa[mt], vf1[n], acc[mt][n], 0, 0, 0);
    }
    // no barrier here: Sp writes of iter n+1 are safe (all Phase-B reads were
    // complete before barrier 2); P2/stats next written only after barrier 1 of n+1.
  }

  // ---- epilogue ----
  float* Ob = O + (size_t)bz * (L_ * E_);
#pragma unroll
  for (int mt = 0; mt < 4; ++mt) {
    f32x4 lv = *(const f32x4*)&l_s[mt * 16 + g * 4];
    float inv[4];
#pragma unroll
    for (int r = 0; r < 4; ++r) inv[r] = 1.0f / lv[r];
#pragma unroll
    for (int n = 0; n < 4; ++n) {
      const int col = w * 64 + n * 16 + ln;
#pragma unroll
      for (int r = 0; r < 4; ++r)
        Ob[(size_t)(q0 + mt * 16 + g * 4 + r) * E_ + col] = acc[mt][n][r] * inv[r];
    }
  }
}

extern "C" void kernel_launch(void* const* d_in, const int* in_sizes, int n_in,
                              void* d_out, int out_size, void* d_ws, size_t ws_size,
                              hipStream_t stream) {
  const float* Q = (const float*)d_in[0];
  const float* K = (const float*)d_in[1];
  const float* V = (const float*)d_in[2];
  float* O = (float*)d_out;
  dim3 grid(32, 16);  // x = q-tile (64 rows), y = batch
  fattn_kernel<<<grid, 512, 0, stream>>>(Q, K, V, O);
}

// Round 3
// 247.503 us; speedup vs baseline: 5.0344x; 1.8034x over previous
//
#include <hip/hip_runtime.h>
#include <hip/hip_bf16.h>

typedef __attribute__((ext_vector_type(8))) short short8;
typedef __attribute__((ext_vector_type(4))) float f32x4;
typedef __attribute__((ext_vector_type(4))) unsigned short us4;

#define L_ 2048
#define E_ 512
#define SCALE 0.04419417382415922f  // 1/sqrt(512)

static __device__ __forceinline__ unsigned short f2bf(float f) {
  return __builtin_bit_cast(unsigned short, __float2bfloat16(f));
}
static __device__ __forceinline__ float bf2f(unsigned short u) {
  return __builtin_bit_cast(float, (unsigned)u << 16);
}

// 8 waves: QK^T split as we(0..3: 128-e chunk) x ws(0..1: 32-s half of 64-s tile).
// Softmax: waves 0..3 each own one 16-q stripe (mt = w); stats canonical in LDS.
// PV: wave w owns d-chunk [w*64, w*64+64); V lives in registers (no LDS staging).
// waves_per_eu(2,2): allow up to 256 VGPRs so qf/acc stay register-resident
// (at 128 the compiler remats Q loads + spills V staging every iteration).
__global__ void
__launch_bounds__(512)
__attribute__((amdgpu_waves_per_eu(2, 2)))
fattn_kernel(const float* __restrict__ Q,
             const float* __restrict__ K,
             const float* __restrict__ V,
             float* __restrict__ O) {
  __shared__ us4 Sp[4][2][4][2][64];        // bf16x4 partial scores [we][ws][mt][nt][lane], 32 KB
  __shared__ unsigned short P2[8][64][8];   // P in A-frag layout [s>>3][q][s&7], 8 KB
  __shared__ float m_s[64], l_s[64], corr_s[64];

  const int tid  = threadIdx.x;
  const int w    = tid >> 6;
  const int lane = tid & 63;
  const int g    = lane >> 4;
  const int ln   = lane & 15;
  const int we   = w >> 1;
  const int ws   = w & 1;
  // 1D grid, strictly descending work order for greedy dynamic balance:
  // t = bid>>4 (0 = heaviest tile), batch = bid & 15.
  const int bid  = (int)blockIdx.x;
  const int bz   = bid & 15;
  const int q0   = (31 - (bid >> 4)) * 64;

  const float* Qb = Q + (size_t)bz * (L_ * E_);
  const float* Kb = K + (size_t)bz * (L_ * E_);
  const float* Vb = V + (size_t)bz * (L_ * E_);

  if (tid < 64) { m_s[tid] = -1e30f; l_s[tid] = 0.f; }

  // Q fragments (SCALE pre-folded), e-chunk we*128, kept in regs all iterations.
  short8 qf[4][4];
#pragma unroll
  for (int mt = 0; mt < 4; ++mt) {
    const float* qp = Qb + (size_t)(q0 + mt * 16 + ln) * E_ + (we * 128 + g * 8);
#pragma unroll
    for (int kc = 0; kc < 4; ++kc) {
      f32x4 a = *(const f32x4*)(qp + kc * 32);
      f32x4 b = *(const f32x4*)(qp + kc * 32 + 4);
      short8 t;
      t[0] = (short)f2bf(a[0] * SCALE); t[1] = (short)f2bf(a[1] * SCALE);
      t[2] = (short)f2bf(a[2] * SCALE); t[3] = (short)f2bf(a[3] * SCALE);
      t[4] = (short)f2bf(b[0] * SCALE); t[5] = (short)f2bf(b[1] * SCALE);
      t[6] = (short)f2bf(b[2] * SCALE); t[7] = (short)f2bf(b[3] * SCALE);
      qf[mt][kc] = t;
    }
  }

  f32x4 acc[4][4];
#pragma unroll
  for (int mt = 0; mt < 4; ++mt)
#pragma unroll
    for (int n = 0; n < 4; ++n) acc[mt][n] = (f32x4){0.f, 0.f, 0.f, 0.f};

  const int nIter = q0 / 64 + 1;   // covers s <= q0+63
  for (int it = 0; it < nIter; ++it) {
    const int s0 = it * 64;

    // ---- Phase A ----
    // Issue first-half V loads (s0..s0+31) for this iter; consumed in Phase C.
    // No barrier precedes this, so these overlap the previous iteration's PV.
    float vr0[4][8];
#pragma unroll
    for (int n = 0; n < 4; ++n) {
      const float* vp = Vb + (size_t)(s0 + g * 8) * E_ + (w * 64 + n * 16 + ln);
#pragma unroll
      for (int i = 0; i < 8; ++i) vr0[n][i] = vp[(size_t)i * E_];
    }

    // QK^T partials: this wave covers 64q x 16s (nt) x 128e (we)
#pragma unroll
    for (int nt = 0; nt < 2; ++nt) {
      f32x4 ps[4];
#pragma unroll
      for (int mt = 0; mt < 4; ++mt) ps[mt] = (f32x4){0.f, 0.f, 0.f, 0.f};
      const float* kp = Kb + (size_t)(s0 + ws * 32 + nt * 16 + ln) * E_ + (we * 128 + g * 8);
#pragma unroll
      for (int kc = 0; kc < 4; ++kc) {
        f32x4 a = *(const f32x4*)(kp + kc * 32);
        f32x4 b = *(const f32x4*)(kp + kc * 32 + 4);
        short8 kf;
        kf[0] = (short)f2bf(a[0]); kf[1] = (short)f2bf(a[1]);
        kf[2] = (short)f2bf(a[2]); kf[3] = (short)f2bf(a[3]);
        kf[4] = (short)f2bf(b[0]); kf[5] = (short)f2bf(b[1]);
        kf[6] = (short)f2bf(b[2]); kf[7] = (short)f2bf(b[3]);
#pragma unroll
        for (int mt = 0; mt < 4; ++mt)
          ps[mt] = __builtin_amdgcn_mfma_f32_16x16x32_bf16(qf[mt][kc], kf, ps[mt], 0, 0, 0);
      }
#pragma unroll
      for (int mt = 0; mt < 4; ++mt) {
        us4 u;
        u[0] = f2bf(ps[mt][0]); u[1] = f2bf(ps[mt][1]);
        u[2] = f2bf(ps[mt][2]); u[3] = f2bf(ps[mt][3]);
        Sp[we][ws][mt][nt][lane] = u;
      }
    }
    __syncthreads();   // barrier 1: Sp ready

    // ---- Phase B: waves 0..3 reduce + online softmax for stripe mt = w ----
    if (w < 4) {
      const int mt = w;
      float p[4][4];
#pragma unroll
      for (int j = 0; j < 4; ++j) {   // j = ws*2 + nt -> s = j*16 + ln
        us4 u0 = Sp[0][j >> 1][mt][j & 1][lane];
        us4 u1 = Sp[1][j >> 1][mt][j & 1][lane];
        us4 u2 = Sp[2][j >> 1][mt][j & 1][lane];
        us4 u3 = Sp[3][j >> 1][mt][j & 1][lane];
#pragma unroll
        for (int r = 0; r < 4; ++r)
          p[j][r] = bf2f(u0[r]) + bf2f(u1[r]) + bf2f(u2[r]) + bf2f(u3[r]);
      }
      if (s0 + 63 > q0) {
#pragma unroll
        for (int j = 0; j < 4; ++j)
#pragma unroll
          for (int r = 0; r < 4; ++r)
            if (s0 + j * 16 + ln > q0 + mt * 16 + g * 4 + r) p[j][r] = -1e30f;
      }
      float tmax[4], lsum[4];
#pragma unroll
      for (int r = 0; r < 4; ++r)
        tmax[r] = fmaxf(fmaxf(p[0][r], p[1][r]), fmaxf(p[2][r], p[3][r]));
#pragma unroll
      for (int off = 1; off < 16; off <<= 1)
#pragma unroll
        for (int r = 0; r < 4; ++r) tmax[r] = fmaxf(tmax[r], __shfl_xor(tmax[r], off));
      f32x4 mr = *(const f32x4*)&m_s[mt * 16 + g * 4];
      float mnew[4], corr[4];
#pragma unroll
      for (int r = 0; r < 4; ++r) {
        mnew[r] = fmaxf(mr[r], tmax[r]);
        corr[r] = __expf(mr[r] - mnew[r]);
        lsum[r] = 0.f;
      }
#pragma unroll
      for (int j = 0; j < 4; ++j)
#pragma unroll
        for (int r = 0; r < 4; ++r) {
          p[j][r] = __expf(p[j][r] - mnew[r]);
          lsum[r] += p[j][r];
        }
#pragma unroll
      for (int off = 1; off < 16; off <<= 1)
#pragma unroll
        for (int r = 0; r < 4; ++r) lsum[r] += __shfl_xor(lsum[r], off);
      if (ln == 0) {
#pragma unroll
        for (int r = 0; r < 4; ++r) {
          const int q = mt * 16 + g * 4 + r;
          m_s[q] = mnew[r];
          corr_s[q] = corr[r];
          l_s[q] = l_s[q] * corr[r] + lsum[r];
        }
      }
#pragma unroll
      for (int j = 0; j < 4; ++j)
#pragma unroll
        for (int r = 0; r < 4; ++r) {
          const int s = j * 16 + ln;
          P2[s >> 3][mt * 16 + g * 4 + r][s & 7] = f2bf(p[j][r]);
        }
    }
    __syncthreads();   // barrier 2: P2 + stats ready

    // ---- Phase C: rescale + PV ----
    // Issue second-half V loads (s0+32..s0+63) now; latency hides under kc=0 MFMAs.
    float vr1[4][8];
#pragma unroll
    for (int n = 0; n < 4; ++n) {
      const float* vp = Vb + (size_t)(s0 + 32 + g * 8) * E_ + (w * 64 + n * 16 + ln);
#pragma unroll
      for (int i = 0; i < 8; ++i) vr1[n][i] = vp[(size_t)i * E_];
    }
    // convert first-half V
    short8 vf0[4];
#pragma unroll
    for (int n = 0; n < 4; ++n) {
      short8 t;
#pragma unroll
      for (int i = 0; i < 8; ++i) t[i] = (short)f2bf(vr0[n][i]);
      vf0[n] = t;
    }
#pragma unroll
    for (int mt = 0; mt < 4; ++mt) {
      f32x4 c4 = *(const f32x4*)&corr_s[mt * 16 + g * 4];
#pragma unroll
      for (int n = 0; n < 4; ++n) {
        acc[mt][n][0] *= c4[0]; acc[mt][n][1] *= c4[1];
        acc[mt][n][2] *= c4[2]; acc[mt][n][3] *= c4[3];
      }
    }
    {
      short8 pa[4];
#pragma unroll
      for (int mt = 0; mt < 4; ++mt)
        pa[mt] = *(const short8*)&P2[g][mt * 16 + ln][0];
#pragma unroll
      for (int n = 0; n < 4; ++n)
#pragma unroll
        for (int mt = 0; mt < 4; ++mt)
          acc[mt][n] = __builtin_amdgcn_mfma_f32_16x16x32_bf16(pa[mt], vf0[n], acc[mt][n], 0, 0, 0);
    }
    {
      short8 vf1[4];
#pragma unroll
      for (int n = 0; n < 4; ++n) {
        short8 t;
#pragma unroll
        for (int i = 0; i < 8; ++i) t[i] = (short)f2bf(vr1[n][i]);
        vf1[n] = t;
      }
      short8 pa[4];
#pragma unroll
      for (int mt = 0; mt < 4; ++mt)
        pa[mt] = *(const short8*)&P2[4 + g][mt * 16 + ln][0];
#pragma unroll
      for (int n = 0; n < 4; ++n)
#pragma unroll
        for (int mt = 0; mt < 4; ++mt)
          acc[mt][n] = __builtin_amdgcn_mfma_f32_16x16x32_bf16(pa[mt], vf1[n], acc[mt][n], 0, 0, 0);
    }
    // no barrier here: Sp writes of iter n+1 are safe (all Phase-B reads were
    // complete before barrier 2); P2/stats next written only after barrier 1 of n+1.
  }

  // ---- epilogue ----
  float* Ob = O + (size_t)bz * (L_ * E_);
#pragma unroll
  for (int mt = 0; mt < 4; ++mt) {
    f32x4 lv = *(const f32x4*)&l_s[mt * 16 + g * 4];
    float inv[4];
#pragma unroll
    for (int r = 0; r < 4; ++r) inv[r] = 1.0f / lv[r];
#pragma unroll
    for (int n = 0; n < 4; ++n) {
      const int col = w * 64 + n * 16 + ln;
#pragma unroll
      for (int r = 0; r < 4; ++r)
        Ob[(size_t)(q0 + mt * 16 + g * 4 + r) * E_ + col] = acc[mt][n][r] * inv[r];
    }
  }
}

extern "C" void kernel_launch(void* const* d_in, const int* in_sizes, int n_in,
                              void* d_out, int out_size, void* d_ws, size_t ws_size,
                              hipStream_t stream) {
  const float* Q = (const float*)d_in[0];
  const float* K = (const float*)d_in[1];
  const float* V = (const float*)d_in[2];
  float* O = (float*)d_out;
  fattn_kernel<<<dim3(512), 512, 0, stream>>>(Q, K, V, O);
}